// Round 1
// 793.213 us; speedup vs baseline: 1.0002x; 1.0002x over previous
//
#include <hip/hip_runtime.h>
#include <hip/hip_bf16.h>
#include <math.h>

// MultiHeadAttention with GELU-instead-of-softmax.
// x:(2,2048,1024) fp32; Wq/Wk/Wv/Wo:(1024,1024); b*:(1024,)
// out = (ctx @ Wo.T + bo)  [2,2048,1024]  +  weights = gelu(QK^T/8) [2,16,2048,2048]
// d_out = out flat (4194304 f32) ++ weights flat (134217728 f32)

using bf16 = __bf16;
typedef __bf16 bf16x8 __attribute__((ext_vector_type(8)));
typedef __bf16 bf16x4 __attribute__((ext_vector_type(4)));
typedef float  floatx4 __attribute__((ext_vector_type(4)));

#define NTOK 4096      // 2*2048 tokens
#define EMB  1024
#define SEQ  2048
#define NH   16
#define HD   64

// Fast exact-enough GELU: tanh form, err <= ~5e-4 abs (absmax budget is bf16-ctx
// dominated at 0.125). gelu(x) = x*(1 - 1/(1+e^{2y})), y = 0.79788456(x+0.044715x^3).
__device__ __forceinline__ float gelu_f(float x) {
    float z = __builtin_fmaf(0.044715f * x, x * x, x);     // x + 0.044715 x^3
    float e = __expf(1.5957691216057308f * z);             // e^{2y}, v_exp_f32 path
    return x - __fdividef(x, 1.0f + e);                    // x*(1 - rcp(1+e))
}

// ---------------------------------------------------------------------------
// Kernel 1: QKV projection. C = x @ W.T + b, M=4096 N=1024 K=1024.
// z=0 -> Q (scaled 1/8) [b,h,n,d] bf16 ; z=1 -> K [b,h,n,d] ; z=2 -> V^T [b,h,d,n]
// Staging repacked: 8 fp32 -> 8 bf16 -> one ds_write_b128 (was 32 ds_write_b16).
// ---------------------------------------------------------------------------
__global__ __launch_bounds__(256) void proj_qkv(
    const float* __restrict__ x,
    const float* __restrict__ Wq, const float* __restrict__ bq,
    const float* __restrict__ Wk, const float* __restrict__ bk,
    const float* __restrict__ Wv, const float* __restrict__ bv,
    bf16* __restrict__ qb, bf16* __restrict__ kb, bf16* __restrict__ vtb)
{
    const int z = blockIdx.z;
    const float* __restrict__ W    = (z == 0) ? Wq : (z == 1) ? Wk : Wv;
    const float* __restrict__ bias = (z == 0) ? bq : (z == 1) ? bk : bv;

    constexpr int BM = 128, BN = 128, BK = 64, SROW = BK + 8; // 144B rows (16B aligned)
    __shared__ bf16 As[BM * SROW];
    __shared__ bf16 Bs[BN * SROW];

    const int m0 = blockIdx.y * BM;
    const int n0 = blockIdx.x * BN;
    const int tid  = threadIdx.x;
    const int wave = tid >> 6, lane = tid & 63;
    const int quad = lane >> 4, r16 = lane & 15;
    const int wm = (wave >> 1) * 64, wn = (wave & 1) * 64;

    floatx4 acc[4][4];
    for (int i = 0; i < 4; i++)
        for (int j = 0; j < 4; j++)
            acc[i][j] = floatx4{0.f, 0.f, 0.f, 0.f};

    for (int k0 = 0; k0 < EMB; k0 += BK) {
        // stage A (x tile fp32 -> bf16): 128x64 = 1024 groups of 8, 4/thread
#pragma unroll
        for (int g = 0; g < 4; g++) {
            int f = tid + g * 256;
            int row = f >> 3, c8 = (f & 7) * 8;
            const float* src = x + (size_t)(m0 + row) * EMB + k0 + c8;
            const float4 v0 = *(const float4*)(src);
            const float4 v1 = *(const float4*)(src + 4);
            bf16x8 o;
            o[0] = (bf16)v0.x; o[1] = (bf16)v0.y; o[2] = (bf16)v0.z; o[3] = (bf16)v0.w;
            o[4] = (bf16)v1.x; o[5] = (bf16)v1.y; o[6] = (bf16)v1.z; o[7] = (bf16)v1.w;
            *(bf16x8*)(As + row * SROW + c8) = o;
        }
        // stage B (W tile rows = output cols)
#pragma unroll
        for (int g = 0; g < 4; g++) {
            int f = tid + g * 256;
            int row = f >> 3, c8 = (f & 7) * 8;
            const float* src = W + (size_t)(n0 + row) * EMB + k0 + c8;
            const float4 v0 = *(const float4*)(src);
            const float4 v1 = *(const float4*)(src + 4);
            bf16x8 o;
            o[0] = (bf16)v0.x; o[1] = (bf16)v0.y; o[2] = (bf16)v0.z; o[3] = (bf16)v0.w;
            o[4] = (bf16)v1.x; o[5] = (bf16)v1.y; o[6] = (bf16)v1.z; o[7] = (bf16)v1.w;
            *(bf16x8*)(Bs + row * SROW + c8) = o;
        }
        __syncthreads();
#pragma unroll
        for (int ks = 0; ks < 2; ks++) {
            bf16x8 af[4], bfr[4];
#pragma unroll
            for (int t = 0; t < 4; t++)
                af[t]  = *(const bf16x8*)(As + (wm + t * 16 + r16) * SROW + ks * 32 + quad * 8);
#pragma unroll
            for (int t = 0; t < 4; t++)
                bfr[t] = *(const bf16x8*)(Bs + (wn + t * 16 + r16) * SROW + ks * 32 + quad * 8);
#pragma unroll
            for (int mt = 0; mt < 4; mt++)
#pragma unroll
                for (int nt = 0; nt < 4; nt++)
                    acc[mt][nt] = __builtin_amdgcn_mfma_f32_16x16x32_bf16(
                        af[mt], bfr[nt], acc[mt][nt], 0, 0, 0);
        }
        __syncthreads();
    }

    // epilogue: +bias, cast, scatter per layout
    for (int mt = 0; mt < 4; mt++)
        for (int nt = 0; nt < 4; nt++)
            for (int i = 0; i < 4; i++) {
                int row = m0 + wm + mt * 16 + quad * 4 + i;   // token 0..4095
                int col = n0 + wn + nt * 16 + r16;            // emb 0..1023
                float v = acc[mt][nt][i] + bias[col];
                int b = row >> 11, n = row & 2047;
                int h = col >> 6,  d = col & 63;
                if (z == 0) {
                    qb[(((size_t)(b * NH + h) * SEQ + n) << 6) + d] = (bf16)(v * 0.125f);
                } else if (z == 1) {
                    kb[(((size_t)(b * NH + h) * SEQ + n) << 6) + d] = (bf16)v;
                } else {
                    vtb[((size_t)((b * NH + h) * HD + d) << 11) + n] = (bf16)v;
                }
            }
}

// ---------------------------------------------------------------------------
// Kernel 2: attention. Per (b,h) and 128-row query tile.
// Restructured:
//  - S^T = mfma(K_frag, Q_frag): lane holds 4 consecutive k -> dwordx4 weight
//    stores + b64 P stores (4x fewer store insts than row-layout).
//  - Q fragments hoisted to registers (loaded once); K/V fragments loaded
//    DIRECTLY from global (L2-resident: 512KB per bh, 16 blocks share it).
//    K prefetched one iteration ahead; V issued at iteration top.
//  - Only Ps in LDS (36.9KB, double-buffered) -> ONE raw s_barrier per iter
//    with lgkmcnt(0) only (no vmcnt drain: weight stores + K prefetch stay
//    in flight across the barrier).
//  - XCD swizzle: 4 bh per XCD so K+V (2MB) sits in that XCD's 4MiB L2.
//  - gelu via fast tanh-form (no erff libcall).
// ---------------------------------------------------------------------------
__global__ __launch_bounds__(256) void attn(
    const bf16* __restrict__ qb, const bf16* __restrict__ kb,
    const bf16* __restrict__ vtb,
    float* __restrict__ wout,     // [32][2048][2048]
    bf16* __restrict__ ctxb)      // [4096][1024]
{
    constexpr int BM = 128, BN = 64, SP = 72;   // SP rows = 144B (16B aligned)
    __shared__ bf16 Ps[2][BM * SP];             // 36864 B total

    // XCD-aware swizzle: 512 blocks round-robin over 8 XCDs by linear id.
    // Give each XCD 4 consecutive bh (all 16 q-tiles of each).
    const int blk  = blockIdx.x + gridDim.x * blockIdx.y;  // 0..511
    const int xcd  = blk & 7, slot = blk >> 3;             // slot 0..63
    const int bh   = xcd * 4 + (slot >> 4);                // 4 bh per XCD
    const int m0   = (slot & 15) * BM;                     // query tile base

    const int tid  = threadIdx.x;
    const int wave = tid >> 6, lane = tid & 63;
    const int quad = lane >> 4, r16 = lane & 15;
    const int wq = (wave >> 1) * 64;   // query sub-tile (S^T cols / PV rows)
    const int wk = (wave & 1) * 32;    // key sub-tile (S^T rows); PV d sub-tile

    const bf16* __restrict__ Q  = qb  + (size_t)bh * SEQ * HD;
    const bf16* __restrict__ K  = kb  + (size_t)bh * SEQ * HD;
    const bf16* __restrict__ Vt = vtb + (size_t)bh * HD * SEQ;
    float* __restrict__ wrow = wout + (size_t)bh * SEQ * SEQ;

    // Q fragments (B-operand), loaded once: 32 VGPRs
    bf16x8 qf[4][2];
#pragma unroll
    for (int qt = 0; qt < 4; qt++)
#pragma unroll
        for (int ks = 0; ks < 2; ks++)
            qf[qt][ks] = *(const bf16x8*)(
                Q + (size_t)(m0 + wq + qt * 16 + r16) * HD + ks * 32 + quad * 8);

    floatx4 ctx[4][2];
    for (int i = 0; i < 4; i++)
        for (int j = 0; j < 2; j++)
            ctx[i][j] = floatx4{0.f, 0.f, 0.f, 0.f};

    // K fragments (A-operand) for first tile
    bf16x8 kf[2][2];
#pragma unroll
    for (int ks = 0; ks < 2; ks++)
#pragma unroll
        for (int kt = 0; kt < 2; kt++)
            kf[kt][ks] = *(const bf16x8*)(
                K + (size_t)(wk + kt * 16 + r16) * HD + ks * 32 + quad * 8);

    for (int nn0 = 0; nn0 < SEQ; nn0 += BN) {
        const int pb = (nn0 >> 6) & 1;

        // V fragments for this tile: issue early, consumed after the barrier
        bf16x8 vf[2][2];
#pragma unroll
        for (int ks = 0; ks < 2; ks++)
#pragma unroll
            for (int nt = 0; nt < 2; nt++)
                vf[nt][ks] = *(const bf16x8*)(
                    Vt + (size_t)(wk + nt * 16 + r16) * SEQ + nn0 + ks * 32 + quad * 8);

        // S^T tile: D[key][query] = K . Q^T   (Q pre-scaled by 1/8)
        floatx4 s[2][4];
        for (int i = 0; i < 2; i++)
            for (int j = 0; j < 4; j++)
                s[i][j] = floatx4{0.f, 0.f, 0.f, 0.f};
#pragma unroll
        for (int ks = 0; ks < 2; ks++)
#pragma unroll
            for (int kt = 0; kt < 2; kt++)
#pragma unroll
                for (int qt = 0; qt < 4; qt++)
                    s[kt][qt] = __builtin_amdgcn_mfma_f32_16x16x32_bf16(
                        kf[kt][ks], qf[qt][ks], s[kt][qt], 0, 0, 0);

        // prefetch next K tile (latency hidden under gelu + PV)
        if (nn0 + BN < SEQ) {
#pragma unroll
            for (int ks = 0; ks < 2; ks++)
#pragma unroll
                for (int kt = 0; kt < 2; kt++)
                    kf[kt][ks] = *(const bf16x8*)(
                        K + (size_t)(nn0 + BN + wk + kt * 16 + r16) * HD + ks * 32 + quad * 8);
        }

        // gelu; lane holds 4 consecutive k for one q -> vectorized stores
#pragma unroll
        for (int kt = 0; kt < 2; kt++)
#pragma unroll
            for (int qt = 0; qt < 4; qt++) {
                const int q  = wq + qt * 16 + r16;
                const int kk = wk + kt * 16 + quad * 4;
                float4 g4;
                g4.x = gelu_f(s[kt][qt][0]);
                g4.y = gelu_f(s[kt][qt][1]);
                g4.z = gelu_f(s[kt][qt][2]);
                g4.w = gelu_f(s[kt][qt][3]);
                *(float4*)(wrow + (size_t)(m0 + q) * SEQ + nn0 + kk) = g4;
                bf16x4 p4;
                p4[0] = (bf16)g4.x; p4[1] = (bf16)g4.y;
                p4[2] = (bf16)g4.z; p4[3] = (bf16)g4.w;
                *(bf16x4*)(&Ps[pb][q * SP + kk]) = p4;
            }

        // Drain own DS ops only (NOT vmcnt: weight stores / K prefetch stay in
        // flight), then barrier: all waves' P writes visible.
        asm volatile("s_waitcnt lgkmcnt(0)" ::: "memory");
        __builtin_amdgcn_s_barrier();

        // ctx += P @ V : A = Ps[q][k], B = Vt[d][k] (bt form), K-dim 64
#pragma unroll
        for (int ks = 0; ks < 2; ks++) {
            bf16x8 af[4];
#pragma unroll
            for (int mt = 0; mt < 4; mt++)
                af[mt] = *(const bf16x8*)(&Ps[pb][(wq + mt * 16 + r16) * SP + ks * 32 + quad * 8]);
#pragma unroll
            for (int mt = 0; mt < 4; mt++)
#pragma unroll
                for (int nt = 0; nt < 2; nt++)
                    ctx[mt][nt] = __builtin_amdgcn_mfma_f32_16x16x32_bf16(
                        af[mt], vf[nt][ks], ctx[mt][nt], 0, 0, 0);
        }
        // no trailing barrier: next iter writes the OTHER Ps buffer; reuse of
        // this buffer is 2 barriers away and each barrier drains own lgkm.
    }

    // epilogue: ctx -> ctxb bf16 at [b*2048+n][h*64+d]
    const int b = bh >> 4, h = bh & 15;
    for (int mt = 0; mt < 4; mt++)
        for (int nt = 0; nt < 2; nt++)
            for (int i = 0; i < 4; i++) {
                int row = m0 + wq + mt * 16 + quad * 4 + i;   // token in [0,2048)
                int d   = wk + nt * 16 + r16;
                ctxb[(size_t)(b * SEQ + row) * EMB + h * HD + d] = (bf16)ctx[mt][nt][i];
            }
}

// ---------------------------------------------------------------------------
// Kernel 3: out = ctx @ Wo.T + bo, M=4096 N=1024 K=1024, A already bf16.
// ---------------------------------------------------------------------------
__global__ __launch_bounds__(256) void outproj(
    const bf16* __restrict__ ctxb, const float* __restrict__ Wo,
    const float* __restrict__ bo, float* __restrict__ out)
{
    constexpr int BM = 128, BN = 128, BK = 64, SROW = BK + 8;
    __shared__ bf16 As[BM * SROW];
    __shared__ bf16 Bs[BN * SROW];

    const int m0 = blockIdx.y * BM;
    const int n0 = blockIdx.x * BN;
    const int tid  = threadIdx.x;
    const int wave = tid >> 6, lane = tid & 63;
    const int quad = lane >> 4, r16 = lane & 15;
    const int wm = (wave >> 1) * 64, wn = (wave & 1) * 64;

    floatx4 acc[4][4];
    for (int i = 0; i < 4; i++)
        for (int j = 0; j < 4; j++)
            acc[i][j] = floatx4{0.f, 0.f, 0.f, 0.f};

    for (int k0 = 0; k0 < EMB; k0 += BK) {
        // stage A (bf16 source): 128x64 bf16 = 1024 x16B, 4/thread
#pragma unroll
        for (int i = 0; i < 4; i++) {
            int f = tid + i * 256;
            int row = f >> 3, c8 = (f & 7) * 8;
            *(uint4*)(As + row * SROW + c8) =
                *(const uint4*)(ctxb + (size_t)(m0 + row) * EMB + k0 + c8);
        }
        // stage B (Wo fp32 -> bf16), repacked 8-wide
#pragma unroll
        for (int g = 0; g < 4; g++) {
            int f = tid + g * 256;
            int row = f >> 3, c8 = (f & 7) * 8;
            const float* src = Wo + (size_t)(n0 + row) * EMB + k0 + c8;
            const float4 v0 = *(const float4*)(src);
            const float4 v1 = *(const float4*)(src + 4);
            bf16x8 o;
            o[0] = (bf16)v0.x; o[1] = (bf16)v0.y; o[2] = (bf16)v0.z; o[3] = (bf16)v0.w;
            o[4] = (bf16)v1.x; o[5] = (bf16)v1.y; o[6] = (bf16)v1.z; o[7] = (bf16)v1.w;
            *(bf16x8*)(Bs + row * SROW + c8) = o;
        }
        __syncthreads();
#pragma unroll
        for (int ks = 0; ks < 2; ks++) {
            bf16x8 af[4], bfr[4];
#pragma unroll
            for (int t = 0; t < 4; t++)
                af[t]  = *(const bf16x8*)(As + (wm + t * 16 + r16) * SROW + ks * 32 + quad * 8);
#pragma unroll
            for (int t = 0; t < 4; t++)
                bfr[t] = *(const bf16x8*)(Bs + (wn + t * 16 + r16) * SROW + ks * 32 + quad * 8);
#pragma unroll
            for (int mt = 0; mt < 4; mt++)
#pragma unroll
                for (int nt = 0; nt < 4; nt++)
                    acc[mt][nt] = __builtin_amdgcn_mfma_f32_16x16x32_bf16(
                        af[mt], bfr[nt], acc[mt][nt], 0, 0, 0);
        }
        __syncthreads();
    }

    for (int mt = 0; mt < 4; mt++)
        for (int nt = 0; nt < 4; nt++)
            for (int i = 0; i < 4; i++) {
                int row = m0 + wm + mt * 16 + quad * 4 + i;
                int col = n0 + wn + nt * 16 + r16;
                out[(size_t)row * EMB + col] = acc[mt][nt][i] + bo[col];
            }
}

// ---------------------------------------------------------------------------
extern "C" void kernel_launch(void* const* d_in, const int* in_sizes, int n_in,
                              void* d_out, int out_size, void* d_ws, size_t ws_size,
                              hipStream_t stream) {
    const float* x  = (const float*)d_in[0];
    const float* Wq = (const float*)d_in[1];
    const float* bq = (const float*)d_in[2];
    const float* Wk = (const float*)d_in[3];
    const float* bk = (const float*)d_in[4];
    const float* Wv = (const float*)d_in[5];
    const float* bv = (const float*)d_in[6];
    const float* Wo = (const float*)d_in[7];
    const float* bo = (const float*)d_in[8];

    float* out  = (float*)d_out;
    float* wout = out + (size_t)NTOK * EMB;   // weights start after out

    bf16* qb   = (bf16*)d_ws;                 //  8 MB
    bf16* kb   = qb  + (size_t)4194304;
    bf16* vtb  = kb  + (size_t)4194304;
    bf16* ctxb = vtb + (size_t)4194304;       // total 32 MB

    proj_qkv<<<dim3(8, 32, 3), 256, 0, stream>>>(x, Wq, bq, Wk, bk, Wv, bv, qb, kb, vtb);
    attn<<<dim3(16, 32), 256, 0, stream>>>(qb, kb, vtb, wout, ctxb);
    outproj<<<dim3(8, 32), 256, 0, stream>>>(ctxb, Wo, bo, out);
}